// Round 20
// baseline (175.290 us; speedup 1.0000x reference)
//
#include <hip/hip_runtime.h>
#include <hip/hip_bf16.h>

// MultiCrossAttention: B=4, T=2048, C=768, H=12, HS=64
// R20: clean composition of measured bests. Dense ktb [b][h][t][64] (linear,
// no XOR) + vtb sigma-only; attn = reg-staged double-buffer (R17 sync) with
// R16's padded-LDS linear-column addressing (6.3e6 conflicts = free 2-way).
// GEMMs XCD-swizzled + merged prepass (R15/R18).

#define B_  4
#define T_  2048
#define C_  768
#define H_  12
#define HS_ 64

typedef __attribute__((ext_vector_type(8))) short short8;   // 8 bf16 (4 VGPRs)
typedef __attribute__((ext_vector_type(4))) float f32x4;

__device__ __forceinline__ short f2bf(float f) {
    __hip_bfloat16 h = __float2bfloat16(f);
    return *reinterpret_cast<short*>(&h);
}

// async global -> LDS, 16B per lane; LDS dest = wave-uniform base + lane*16
__device__ __forceinline__ void gload_lds16(const void* g, void* l) {
    __builtin_amdgcn_global_load_lds((const __attribute__((address_space(1))) void*)g,
                                     (__attribute__((address_space(3))) void*)l,
                                     16, 0, 0);
}

// ---------------- prepass: cvt(x), cvt(memory), transpose 3 weights ----------

__global__ void prepass(const float* __restrict__ x, short* __restrict__ xb,
                        const float* __restrict__ mem, short* __restrict__ memb,
                        const float* __restrict__ Wq,  short* __restrict__ WqT,
                        const float* __restrict__ Wkv, short* __restrict__ WkvT,
                        const float* __restrict__ Wp,  short* __restrict__ WpT,
                        float qscale) {
    const int n4 = 8192 * 768 / 4;          // float4 per tensor
    const int cvtblocks = (2 * n4) / 256;   // 12288
    int bid = blockIdx.x;
    if (bid < cvtblocks) {
        int i = bid * 256 + threadIdx.x;
        const float* in; short* out;
        if (i < n4) { in = x; out = xb; }
        else        { in = mem; out = memb; i -= n4; }
        float4 v = reinterpret_cast<const float4*>(in)[i];
        short4 o;
        o.x = f2bf(v.x); o.y = f2bf(v.y); o.z = f2bf(v.z); o.w = f2bf(v.w);
        reinterpret_cast<short4*>(out)[i] = o;
        return;
    }
    // tiled transpose: out[n][k] = bf16(in[k][n]*sc), 32x32 tiles via LDS
    __shared__ float tile[32][33];
    bid -= cvtblocks;
    const float* in; short* out; int N; float sc = 1.0f;
    if (bid < 576)       { in = Wq;  out = WqT;  N = 768;  sc = qscale; }
    else if (bid < 1728) { in = Wkv; out = WkvT; N = 1536; bid -= 576; }
    else                 { in = Wp;  out = WpT;  N = 768;  bid -= 1728; }
    const int tiles_n = N >> 5;
    const int k0 = (bid / tiles_n) * 32;
    const int n0 = (bid % tiles_n) * 32;
    const int r = threadIdx.x >> 5;     // 0..7
    const int c = threadIdx.x & 31;
    #pragma unroll
    for (int i = 0; i < 4; ++i)
        tile[r + 8 * i][c] = in[(size_t)(k0 + r + 8 * i) * N + n0 + c];
    __syncthreads();
    #pragma unroll
    for (int i = 0; i < 4; ++i)
        out[(size_t)(n0 + r + 8 * i) * 768 + k0 + c] = f2bf(tile[c][r + 8 * i] * sc);
}

// ---------------- GEMM bodies (m97 structure) ----------------

template<int OUT_F32, int WRITE_KV>
__device__ __forceinline__ void gemm_body(const short* __restrict__ A, const short* __restrict__ BT,
                                          const float* __restrict__ bias, void* __restrict__ out,
                                          short* __restrict__ kt, short* __restrict__ vt,
                                          int m0, int n0, int K, int ldo, float bscale,
                                          short (*As)[64], short (*Bs)[64]) {
    const int t  = threadIdx.x;
    const int wid = t >> 6;
    const int wm = wid >> 1, wn = wid & 1;
    const int lane = t & 63;
    const int lr = lane & 15;
    const int lk = (lane >> 4) * 8;

    f32x4 acc[4][4] = {};

    const int srow = wid * 32 + (lane >> 3);   // staging row (+ i*8)
    const int scol = (lane & 7) * 8;           // staging col (shorts)

    for (int k0 = 0; k0 < K; k0 += 64) {
        __syncthreads();
        #pragma unroll
        for (int i = 0; i < 4; ++i)
            gload_lds16(&A[(size_t)(m0 + srow + i * 8) * K + k0 + scol],
                        &As[wid * 32 + i * 8][0]);
        #pragma unroll
        for (int i = 0; i < 4; ++i)
            gload_lds16(&BT[(size_t)(n0 + srow + i * 8) * K + k0 + scol],
                        &Bs[wid * 32 + i * 8][0]);
        __syncthreads();

        #pragma unroll
        for (int ks = 0; ks < 2; ++ks) {
            const int kk = ks * 32 + lk;
            short8 a[4], b[4];
            #pragma unroll
            for (int m = 0; m < 4; ++m)
                a[m] = *reinterpret_cast<const short8*>(&As[wm*64 + m*16 + lr][kk]);
            #pragma unroll
            for (int n = 0; n < 4; ++n)
                b[n] = *reinterpret_cast<const short8*>(&Bs[wn*64 + n*16 + lr][kk]);
            #pragma unroll
            for (int m = 0; m < 4; ++m)
                #pragma unroll
                for (int n = 0; n < 4; ++n)
                    acc[m][n] = __builtin_amdgcn_mfma_f32_16x16x32_bf16(a[m], b[n], acc[m][n], 0, 0, 0);
        }
    }

    const int rb = m0 + wm * 64;
    const int cb = n0 + wn * 64;
    const int rj = (lane >> 4) * 4;
    #pragma unroll
    for (int n = 0; n < 4; ++n) {
        const int col = cb + n * 16 + lr;
        const float bv = bias[col] * bscale;
        #pragma unroll
        for (int m = 0; m < 4; ++m) {
            #pragma unroll
            for (int j = 0; j < 4; ++j) {
                const int row = rb + m * 16 + rj + j;
                const float v = acc[m][n][j] + bv;
                if (WRITE_KV) {
                    const int bb = row >> 11, tt = row & 2047;
                    if (col < 768) {
                        // K -> ktb [b][h][t][64] (dense rows, linear)
                        const int hh = col >> 6, dd = col & 63;
                        kt[(((size_t)bb * H_ + hh) * T_ + tt) * 64 + dd] = f2bf(v);
                    } else {
                        // V -> vtb [b][h][64][T], sigma within chunk (matches attn)
                        const int vd = col - 768;
                        const int hh = vd >> 6, dd = vd & 63;
                        const int kv = tt & 63;
                        const int slot = 32 * (kv >> 5) + 8 * ((kv >> 2) & 3)
                                       + 4 * ((kv >> 4) & 1) + (kv & 3);
                        vt[(((size_t)bb * H_ + hh) * HS_ + dd) * T_ + (tt & ~63) + slot] = f2bf(v);
                    }
                } else if (OUT_F32) {
                    reinterpret_cast<float*>(out)[(size_t)row * ldo + col] = v;
                } else {
                    reinterpret_cast<short*>(out)[(size_t)row * ldo + col] = f2bf(v);
                }
            }
        }
    }
}

// merged q + kv projection GEMM: grid (18, 64), chunked XCD swizzle
__global__ void gemm_qkv(const short* __restrict__ xb,  const short* __restrict__ memb,
                         const short* __restrict__ WqT, const short* __restrict__ WkvT,
                         const float* __restrict__ bq,  const float* __restrict__ bkv,
                         short* __restrict__ qb, short* __restrict__ kt,
                         short* __restrict__ vt, float qscale) {
    __shared__ short As[128][64];
    __shared__ short Bs[128][64];
    const int lin = blockIdx.y * 18 + blockIdx.x;
    const int swz = (lin % 8) * 144 + lin / 8;
    const int bx = swz % 18;
    const int m0 = (swz / 18) * 128;
    if (bx < 6) {
        gemm_body<0,0>(xb, WqT, bq, qb, nullptr, nullptr, m0, bx * 128, 768, 768, qscale, As, Bs);
    } else {
        gemm_body<0,1>(memb, WkvT, bkv, nullptr, kt, vt, m0, (bx - 6) * 128, 768, 1536, 1.0f, As, Bs);
    }
}

// output projection GEMM (f32 out): grid (6, 64), chunked XCD swizzle
__global__ void gemm_out(const short* __restrict__ yb, const short* __restrict__ WpT,
                         const float* __restrict__ bproj, float* __restrict__ out) {
    __shared__ short As[128][64];
    __shared__ short Bs[128][64];
    const int lin = blockIdx.y * 6 + blockIdx.x;
    const int swz = (lin % 8) * 48 + lin / 8;
    gemm_body<1,0>(yb, WpT, bproj, out, nullptr, nullptr, (swz / 6) * 128, (swz % 6) * 128,
                   768, 768, 1.0f, As, Bs);
}

// ---------------- flash attention (reg-staged dbuf, padded LDS, linear cols) -
// grid 768 = 16 qblk x 48 pairs. Block 256 = 4 waves, wave owns 32 q-rows.
// Per chunk: ds_write buf[c] -> issue loads t+1 (fly under barrier+compute)
// -> barrier -> compute buf[c] -> c^=1. K from dense ktb [t][64]; V from vtb
// (sigma in global). LDS padded [2][64][72]; reads at linear col ks*32+g*8
// (2-way bank aliasing = free, m136). Swapped QK^T (lane owns a q-row of P),
// register-local PV A-frag, ones-MFMA l, shift-free softmax (Wq pre-scaled).

__global__ void __launch_bounds__(256)
attn_fwd17(const short* __restrict__ qb, const short* __restrict__ ktb,
           const short* __restrict__ vtb, short* __restrict__ yb) {
    __shared__ short Ks[2][64][72];
    __shared__ short Vt[2][64][72];

    const int id = blockIdx.x;
    const int pair = id % 48;        // b*H + h
    const int b = pair / H_, h = pair % H_;
    const int q0 = (id / 48) * 128;
    const int t = threadIdx.x;
    const int w = t >> 6;
    const int lane = t & 63;
    const int lr = lane & 15;
    const int g = lane >> 4;

    const int str = t >> 2;          // staging row 0..63 (4 threads/row)
    const int stc = (t & 3) * 16;    // staging col base (shorts)

    const short* Kb = ktb + (size_t)(b * H_ + h) * T_ * 64;
    const short* Vb = vtb + (size_t)(b * H_ + h) * HS_ * T_;

    // Q fragments: tile m rows q0 + w*32 + m*16 + lr, k = ks*32+g*8
    short8 aq[2][2];
    #pragma unroll
    for (int m = 0; m < 2; ++m)
        #pragma unroll
        for (int ks = 0; ks < 2; ++ks)
            aq[m][ks] = *reinterpret_cast<const short8*>(
                &qb[(size_t)(b * T_ + q0 + w * 32 + m * 16 + lr) * C_ + h * HS_ + ks * 32 + g * 8]);

    // all-ones bf16 B-fragment for the l-sum MFMA
    short8 ones8;
    #pragma unroll
    for (int i = 0; i < 8; ++i) ones8[i] = (short)0x3F80;

    f32x4 acc[2][4] = {};
    f32x4 accl[2] = {};

    // prologue: load chunk 0 into regs (K rows dense 64-wide; V rows T-wide)
    uint4 kr0, kr1, vr0, vr1;
    {
        const short* gk = &Kb[(size_t)str * 64 + stc];
        const short* gv = &Vb[(size_t)str * T_ + stc];
        kr0 = *reinterpret_cast<const uint4*>(gk);
        kr1 = *reinterpret_cast<const uint4*>(gk + 8);
        vr0 = *reinterpret_cast<const uint4*>(gv);
        vr1 = *reinterpret_cast<const uint4*>(gv + 8);
    }

    int c = 0;
    for (int kv0 = 0; kv0 < T_; kv0 += 64) {
        // stage chunk t into buf[c] (safe: last readers finished before the
        // iter t-1 barrier, which precedes this write)
        *reinterpret_cast<uint4*>(&Ks[c][str][stc])     = kr0;
        *reinterpret_cast<uint4*>(&Ks[c][str][stc + 8]) = kr1;
        *reinterpret_cast<uint4*>(&Vt[c][str][stc])     = vr0;
        *reinterpret_cast<uint4*>(&Vt[c][str][stc + 8]) = vr1;

        // issue loads for chunk t+1 before the barrier
        if (kv0 + 64 < T_) {
            const short* gk = &Kb[(size_t)(kv0 + 64 + str) * 64 + stc];
            const short* gv = &Vb[(size_t)str * T_ + kv0 + 64 + stc];
            kr0 = *reinterpret_cast<const uint4*>(gk);
            kr1 = *reinterpret_cast<const uint4*>(gk + 8);
            vr0 = *reinterpret_cast<const uint4*>(gv);
            vr1 = *reinterpret_cast<const uint4*>(gv + 8);
        }

        __syncthreads();   // buf[c] fully staged by all waves

        // S^T = K Q^T for both m-tiles (bk read once, used twice)
        f32x4 s[2][4] = {};
        #pragma unroll
        for (int ks = 0; ks < 2; ++ks) {
            #pragma unroll
            for (int n = 0; n < 4; ++n) {
                short8 bk = *reinterpret_cast<const short8*>(&Ks[c][n * 16 + lr][ks * 32 + g * 8]);
                #pragma unroll
                for (int m = 0; m < 2; ++m)
                    s[m][n] = __builtin_amdgcn_mfma_f32_16x16x32_bf16(bk, aq[m][ks], s[m][n], 0, 0, 0);
            }
        }

        // P = exp2(S), pack PV A-frags (register-local under sigma)
        short8 pa[2][2];
        #pragma unroll
        for (int m = 0; m < 2; ++m) {
            #pragma unroll
            for (int n = 0; n < 4; ++n) {
                #pragma unroll
                for (int j = 0; j < 4; ++j)
                    s[m][n][j] = exp2f(s[m][n][j]);
            }
            #pragma unroll
            for (int ks = 0; ks < 2; ++ks) {
                pa[m][ks][0] = f2bf(s[m][2*ks][0]); pa[m][ks][1] = f2bf(s[m][2*ks][1]);
                pa[m][ks][2] = f2bf(s[m][2*ks][2]); pa[m][ks][3] = f2bf(s[m][2*ks][3]);
                pa[m][ks][4] = f2bf(s[m][2*ks+1][0]); pa[m][ks][5] = f2bf(s[m][2*ks+1][1]);
                pa[m][ks][6] = f2bf(s[m][2*ks+1][2]); pa[m][ks][7] = f2bf(s[m][2*ks+1][3]);
            }
        }

        // Y += P @ V ; l += P @ ones (bv read once, used by both m)
        #pragma unroll
        for (int ks = 0; ks < 2; ++ks) {
            #pragma unroll
            for (int m = 0; m < 2; ++m)
                accl[m] = __builtin_amdgcn_mfma_f32_16x16x32_bf16(pa[m][ks], ones8, accl[m], 0, 0, 0);
            #pragma unroll
            for (int n = 0; n < 4; ++n) {
                short8 bv = *reinterpret_cast<const short8*>(&Vt[c][n * 16 + lr][ks * 32 + g * 8]);
                #pragma unroll
                for (int m = 0; m < 2; ++m)
                    acc[m][n] = __builtin_amdgcn_mfma_f32_16x16x32_bf16(pa[m][ks], bv, acc[m][n], 0, 0, 0);
            }
        }

        c ^= 1;
    }

    // epilogue: y = acc / l ; accl[m][j] holds l for q-row g*4+j of tile m
    #pragma unroll
    for (int m = 0; m < 2; ++m) {
        #pragma unroll
        for (int j = 0; j < 4; ++j) {
            const float inv = 1.f / accl[m][j];
            const size_t row = (size_t)(b * T_ + q0 + w * 32 + m * 16 + g * 4 + j);
            #pragma unroll
            for (int n = 0; n < 4; ++n)
                yb[row * C_ + h * HS_ + n * 16 + lr] = f2bf(acc[m][n][j] * inv);
        }
    }
}

// ---------------- launch ----------------

extern "C" void kernel_launch(void* const* d_in, const int* in_sizes, int n_in,
                              void* d_out, int out_size, void* d_ws, size_t ws_size,
                              hipStream_t stream) {
    const float* x      = (const float*)d_in[0];
    const float* memory = (const float*)d_in[1];
    const float* Wq     = (const float*)d_in[2];
    const float* bq     = (const float*)d_in[3];
    const float* Wkv    = (const float*)d_in[4];
    const float* bkv    = (const float*)d_in[5];
    const float* Wproj  = (const float*)d_in[6];
    const float* bproj  = (const float*)d_in[7];

    char* ws = (char*)d_ws;
    size_t off = 0;
    auto alloc = [&](size_t bytes) { char* p = ws + off; off += (bytes + 255) & ~(size_t)255; return p; };
    short* xb   = (short*)alloc((size_t)8192 * 768 * 2);   // x bf16, reused as y after attention
    short* memb = (short*)alloc((size_t)8192 * 768 * 2);
    short* qb   = (short*)alloc((size_t)8192 * 768 * 2);
    short* ktb  = (short*)alloc((size_t)B_ * H_ * T_ * 64 * 2);   // K dense [t][64]
    short* vtb  = (short*)alloc((size_t)B_ * H_ * HS_ * T_ * 2);  // V^T, sigma cols
    short* WqT  = (short*)alloc((size_t)768 * 768 * 2);
    short* WkvT = (short*)alloc((size_t)1536 * 768 * 2);
    short* WpT  = (short*)alloc((size_t)768 * 768 * 2);

    // scale folded into Wq/bq: log2(e)/sqrt(HS) -> attention P = exp2(S) raw
    const float qscale = 1.4426950408889634f / 8.0f;

    prepass<<<12288 + 2304, 256, 0, stream>>>(x, xb, memory, memb,
                                              Wq, WqT, Wkv, WkvT, Wproj, WpT, qscale);
    gemm_qkv<<<dim3(18, 64), 256, 0, stream>>>(xb, memb, WqT, WkvT, bq, bkv, qb, ktb, vtb, qscale);
    attn_fwd17<<<dim3(16 * 48), 256, 0, stream>>>(qb, ktb, vtb, xb /* y reuses xb */);
    gemm_out<<<dim3(6, 64), 256, 0, stream>>>(xb, WpT, bproj, (float*)d_out);
}

// Round 21
// 172.502 us; speedup vs baseline: 1.0162x; 1.0162x over previous
//
#include <hip/hip_runtime.h>
#include <hip/hip_bf16.h>

// MultiCrossAttention: B=4, T=2048, C=768, H=12, HS=64
// R21: R18's exact GEMM/prepass/layouts (XOR'd ktb/vtb) + attn with
// TRIPLE-buffered global_load_lds staging and counted s_waitcnt vmcnt(4)
// before a raw s_barrier (never drain to 0 in the loop — T3/T4). Loads get
// two full compute phases to land; barrier cost = pure execution sync.

#define B_  4
#define T_  2048
#define C_  768
#define H_  12
#define HS_ 64

typedef __attribute__((ext_vector_type(8))) short short8;   // 8 bf16 (4 VGPRs)
typedef __attribute__((ext_vector_type(4))) float f32x4;

__device__ __forceinline__ short f2bf(float f) {
    __hip_bfloat16 h = __float2bfloat16(f);
    return *reinterpret_cast<short*>(&h);
}

// async global -> LDS, 16B per lane; LDS dest = wave-uniform base + lane*16
__device__ __forceinline__ void gload_lds16(const void* g, void* l) {
    __builtin_amdgcn_global_load_lds((const __attribute__((address_space(1))) void*)g,
                                     (__attribute__((address_space(3))) void*)l,
                                     16, 0, 0);
}

// ---------------- prepass: cvt(x), cvt(memory), transpose 3 weights ----------

__global__ void prepass(const float* __restrict__ x, short* __restrict__ xb,
                        const float* __restrict__ mem, short* __restrict__ memb,
                        const float* __restrict__ Wq,  short* __restrict__ WqT,
                        const float* __restrict__ Wkv, short* __restrict__ WkvT,
                        const float* __restrict__ Wp,  short* __restrict__ WpT,
                        float qscale) {
    const int n4 = 8192 * 768 / 4;          // float4 per tensor
    const int cvtblocks = (2 * n4) / 256;   // 12288
    int bid = blockIdx.x;
    if (bid < cvtblocks) {
        int i = bid * 256 + threadIdx.x;
        const float* in; short* out;
        if (i < n4) { in = x; out = xb; }
        else        { in = mem; out = memb; i -= n4; }
        float4 v = reinterpret_cast<const float4*>(in)[i];
        short4 o;
        o.x = f2bf(v.x); o.y = f2bf(v.y); o.z = f2bf(v.z); o.w = f2bf(v.w);
        reinterpret_cast<short4*>(out)[i] = o;
        return;
    }
    // tiled transpose: out[n][k] = bf16(in[k][n]*sc), 32x32 tiles via LDS
    __shared__ float tile[32][33];
    bid -= cvtblocks;
    const float* in; short* out; int N; float sc = 1.0f;
    if (bid < 576)       { in = Wq;  out = WqT;  N = 768;  sc = qscale; }
    else if (bid < 1728) { in = Wkv; out = WkvT; N = 1536; bid -= 576; }
    else                 { in = Wp;  out = WpT;  N = 768;  bid -= 1728; }
    const int tiles_n = N >> 5;
    const int k0 = (bid / tiles_n) * 32;
    const int n0 = (bid % tiles_n) * 32;
    const int r = threadIdx.x >> 5;     // 0..7
    const int c = threadIdx.x & 31;
    #pragma unroll
    for (int i = 0; i < 4; ++i)
        tile[r + 8 * i][c] = in[(size_t)(k0 + r + 8 * i) * N + n0 + c];
    __syncthreads();
    #pragma unroll
    for (int i = 0; i < 4; ++i)
        out[(size_t)(n0 + r + 8 * i) * 768 + k0 + c] = f2bf(tile[c][r + 8 * i] * sc);
}

// ---------------- GEMM bodies (m97 structure) ----------------

template<int OUT_F32, int WRITE_KV>
__device__ __forceinline__ void gemm_body(const short* __restrict__ A, const short* __restrict__ BT,
                                          const float* __restrict__ bias, void* __restrict__ out,
                                          short* __restrict__ kt, short* __restrict__ vt,
                                          int m0, int n0, int K, int ldo, float bscale,
                                          short (*As)[64], short (*Bs)[64]) {
    const int t  = threadIdx.x;
    const int wid = t >> 6;
    const int wm = wid >> 1, wn = wid & 1;
    const int lane = t & 63;
    const int lr = lane & 15;
    const int lk = (lane >> 4) * 8;

    f32x4 acc[4][4] = {};

    const int srow = wid * 32 + (lane >> 3);   // staging row (+ i*8)
    const int scol = (lane & 7) * 8;           // staging col (shorts)

    for (int k0 = 0; k0 < K; k0 += 64) {
        __syncthreads();
        #pragma unroll
        for (int i = 0; i < 4; ++i)
            gload_lds16(&A[(size_t)(m0 + srow + i * 8) * K + k0 + scol],
                        &As[wid * 32 + i * 8][0]);
        #pragma unroll
        for (int i = 0; i < 4; ++i)
            gload_lds16(&BT[(size_t)(n0 + srow + i * 8) * K + k0 + scol],
                        &Bs[wid * 32 + i * 8][0]);
        __syncthreads();

        #pragma unroll
        for (int ks = 0; ks < 2; ++ks) {
            const int kk = ks * 32 + lk;
            short8 a[4], b[4];
            #pragma unroll
            for (int m = 0; m < 4; ++m)
                a[m] = *reinterpret_cast<const short8*>(&As[wm*64 + m*16 + lr][kk]);
            #pragma unroll
            for (int n = 0; n < 4; ++n)
                b[n] = *reinterpret_cast<const short8*>(&Bs[wn*64 + n*16 + lr][kk]);
            #pragma unroll
            for (int m = 0; m < 4; ++m)
                #pragma unroll
                for (int n = 0; n < 4; ++n)
                    acc[m][n] = __builtin_amdgcn_mfma_f32_16x16x32_bf16(a[m], b[n], acc[m][n], 0, 0, 0);
        }
    }

    const int rb = m0 + wm * 64;
    const int cb = n0 + wn * 64;
    const int rj = (lane >> 4) * 4;
    #pragma unroll
    for (int n = 0; n < 4; ++n) {
        const int col = cb + n * 16 + lr;
        const float bv = bias[col] * bscale;
        #pragma unroll
        for (int m = 0; m < 4; ++m) {
            #pragma unroll
            for (int j = 0; j < 4; ++j) {
                const int row = rb + m * 16 + rj + j;
                const float v = acc[m][n][j] + bv;
                if (WRITE_KV) {
                    const int bb = row >> 11, tt = row & 2047;
                    if (col < 768) {
                        // K -> ktb [b][h][t][64], 16B-block XOR by (t&7)
                        const int hh = col >> 6, dd = col & 63;
                        const int s = ((((dd >> 3) ^ (tt & 7)) << 3) | (dd & 7));
                        kt[(((size_t)bb * H_ + hh) * T_ + tt) * 64 + s] = f2bf(v);
                    } else {
                        // V -> vtb [b][h][64][T], sigma within chunk + block XOR by (d&7)
                        const int vd = col - 768;
                        const int hh = vd >> 6, dd = vd & 63;
                        const int kv = tt & 63;
                        const int slot = 32 * (kv >> 5) + 8 * ((kv >> 2) & 3)
                                       + 4 * ((kv >> 4) & 1) + (kv & 3);
                        const int slot2 = (((slot >> 3) ^ (dd & 7)) << 3) | (slot & 7);
                        vt[(((size_t)bb * H_ + hh) * HS_ + dd) * T_ + (tt & ~63) + slot2] = f2bf(v);
                    }
                } else if (OUT_F32) {
                    reinterpret_cast<float*>(out)[(size_t)row * ldo + col] = v;
                } else {
                    reinterpret_cast<short*>(out)[(size_t)row * ldo + col] = f2bf(v);
                }
            }
        }
    }
}

// merged q + kv projection GEMM: grid (18, 64), chunked XCD swizzle
__global__ void gemm_qkv(const short* __restrict__ xb,  const short* __restrict__ memb,
                         const short* __restrict__ WqT, const short* __restrict__ WkvT,
                         const float* __restrict__ bq,  const float* __restrict__ bkv,
                         short* __restrict__ qb, short* __restrict__ kt,
                         short* __restrict__ vt, float qscale) {
    __shared__ short As[128][64];
    __shared__ short Bs[128][64];
    const int lin = blockIdx.y * 18 + blockIdx.x;
    const int swz = (lin % 8) * 144 + lin / 8;
    const int bx = swz % 18;
    const int m0 = (swz / 18) * 128;
    if (bx < 6) {
        gemm_body<0,0>(xb, WqT, bq, qb, nullptr, nullptr, m0, bx * 128, 768, 768, qscale, As, Bs);
    } else {
        gemm_body<0,1>(memb, WkvT, bkv, nullptr, kt, vt, m0, (bx - 6) * 128, 768, 1536, 1.0f, As, Bs);
    }
}

// output projection GEMM (f32 out): grid (6, 64), chunked XCD swizzle
__global__ void gemm_out(const short* __restrict__ yb, const short* __restrict__ WpT,
                         const float* __restrict__ bproj, float* __restrict__ out) {
    __shared__ short As[128][64];
    __shared__ short Bs[128][64];
    const int lin = blockIdx.y * 6 + blockIdx.x;
    const int swz = (lin % 8) * 48 + lin / 8;
    gemm_body<1,0>(yb, WpT, bproj, out, nullptr, nullptr, (swz / 6) * 128, (swz % 6) * 128,
                   768, 768, 1.0f, As, Bs);
}

// ---------------- flash attention (3-buf gload_lds, counted vmcnt) ----------
// grid 768 = 16 qblk x 48 pairs. Block 256 = 4 waves, wave owns 32 q-rows.
// Per iter t: s_waitcnt vmcnt(4) (retires buf[t%3]'s loads — issued TWO
// compute phases ago; the newest 4 for t+1 stay in flight) -> raw s_barrier
// (all waves' buf[t] loads landed; buf[(t+2)%3] freed, last read at t-1) ->
// stage(t+2) -> compute buf[t%3]. Last iter uses vmcnt(0). K/V global
// layouts carry a 16B-block XOR so linear-staged LDS reads at
// blk' = (ks*4+g)^(lr&7) are conflict-free. Swapped QK^T (lane owns a q-row
// of P), register-local PV A-frag (sigma), ones-MFMA l, shift-free softmax.

__global__ void __launch_bounds__(256)
attn_fwd18(const short* __restrict__ qb, const short* __restrict__ ktb,
           const short* __restrict__ vtb, short* __restrict__ yb) {
    __shared__ short Ks[3][64][64];
    __shared__ short Vt[3][64][64];

    const int id = blockIdx.x;
    const int pair = id % 48;        // b*H + h
    const int b = pair / H_, h = pair % H_;
    const int q0 = (id / 48) * 128;
    const int t = threadIdx.x;
    const int w = t >> 6;
    const int lane = t & 63;
    const int lr = lane & 15;
    const int g = lane >> 4;

    const short* Kb = ktb + (size_t)(b * H_ + h) * T_ * 64;
    const short* Vb = vtb + (size_t)(b * H_ + h) * HS_ * T_;

    // Q fragments first (before staging loads, for clean vmcnt accounting)
    short8 aq[2][2];
    #pragma unroll
    for (int m = 0; m < 2; ++m)
        #pragma unroll
        for (int ks = 0; ks < 2; ++ks)
            aq[m][ks] = *reinterpret_cast<const short8*>(
                &qb[(size_t)(b * T_ + q0 + w * 32 + m * 16 + lr) * C_ + h * HS_ + ks * 32 + g * 8]);

    // all-ones bf16 B-fragment for the l-sum MFMA
    short8 ones8;
    #pragma unroll
    for (int i = 0; i < 8; ++i) ones8[i] = (short)0x3F80;

    f32x4 acc[2][4] = {};
    f32x4 accl[2] = {};

    // stage chunk kv0 into buffer c: wave w stages rows [16w,16w+16) of K and V
    // (4 gload_lds16 per wave per stage -> 4 vmcnt slots)
    auto stage = [&](int kv0, int c) {
        #pragma unroll
        for (int i = 0; i < 2; ++i) {
            gload_lds16(Kb + (size_t)(kv0 + w * 16 + i * 8 + (lane >> 3)) * 64 + (lane & 7) * 8,
                        &Ks[c][w * 16 + i * 8][0]);
            gload_lds16(Vb + (size_t)(w * 16 + i * 8 + (lane >> 3)) * T_ + kv0 + (lane & 7) * 8,
                        &Vt[c][w * 16 + i * 8][0]);
        }
    };

    stage(0, 0);
    stage(64, 1);

    for (int it = 0; it < 32; ++it) {
        const int c = it % 3;
        // retire buf[c]'s 4 loads (oldest); keep the newest 4 in flight.
        if (it == 31) asm volatile("s_waitcnt vmcnt(0)" ::: "memory");
        else          asm volatile("s_waitcnt vmcnt(4)" ::: "memory");
        __builtin_amdgcn_s_barrier();          // all waves' buf[c] loads landed
        __builtin_amdgcn_sched_barrier(0);     // pin: no motion across the sync
        if (it + 2 < 32) stage((it + 2) * 64, (it + 2) % 3);

        // S^T = K Q^T for both m-tiles (bk read once, used twice)
        f32x4 s[2][4] = {};
        #pragma unroll
        for (int ks = 0; ks < 2; ++ks) {
            #pragma unroll
            for (int n = 0; n < 4; ++n) {
                short8 bk = *reinterpret_cast<const short8*>(
                    &Ks[c][n * 16 + lr][(((ks * 4 + g) ^ (lr & 7)) << 3)]);
                #pragma unroll
                for (int m = 0; m < 2; ++m)
                    s[m][n] = __builtin_amdgcn_mfma_f32_16x16x32_bf16(bk, aq[m][ks], s[m][n], 0, 0, 0);
            }
        }

        // P = exp2(S), pack PV A-frags (register-local under sigma)
        short8 pa[2][2];
        #pragma unroll
        for (int m = 0; m < 2; ++m) {
            #pragma unroll
            for (int n = 0; n < 4; ++n) {
                #pragma unroll
                for (int j = 0; j < 4; ++j)
                    s[m][n][j] = exp2f(s[m][n][j]);
            }
            #pragma unroll
            for (int ks = 0; ks < 2; ++ks) {
                pa[m][ks][0] = f2bf(s[m][2*ks][0]); pa[m][ks][1] = f2bf(s[m][2*ks][1]);
                pa[m][ks][2] = f2bf(s[m][2*ks][2]); pa[m][ks][3] = f2bf(s[m][2*ks][3]);
                pa[m][ks][4] = f2bf(s[m][2*ks+1][0]); pa[m][ks][5] = f2bf(s[m][2*ks+1][1]);
                pa[m][ks][6] = f2bf(s[m][2*ks+1][2]); pa[m][ks][7] = f2bf(s[m][2*ks+1][3]);
            }
        }

        // Y += P @ V ; l += P @ ones (bv read once, used by both m)
        #pragma unroll
        for (int ks = 0; ks < 2; ++ks) {
            #pragma unroll
            for (int m = 0; m < 2; ++m)
                accl[m] = __builtin_amdgcn_mfma_f32_16x16x32_bf16(pa[m][ks], ones8, accl[m], 0, 0, 0);
            #pragma unroll
            for (int n = 0; n < 4; ++n) {
                short8 bv = *reinterpret_cast<const short8*>(
                    &Vt[c][n * 16 + lr][(((ks * 4 + g) ^ (lr & 7)) << 3)]);
                #pragma unroll
                for (int m = 0; m < 2; ++m)
                    acc[m][n] = __builtin_amdgcn_mfma_f32_16x16x32_bf16(pa[m][ks], bv, acc[m][n], 0, 0, 0);
            }
        }
    }

    // epilogue: y = acc / l ; accl[m][j] holds l for q-row g*4+j of tile m
    #pragma unroll
    for (int m = 0; m < 2; ++m) {
        #pragma unroll
        for (int j = 0; j < 4; ++j) {
            const float inv = 1.f / accl[m][j];
            const size_t row = (size_t)(b * T_ + q0 + w * 32 + m * 16 + g * 4 + j);
            #pragma unroll
            for (int n = 0; n < 4; ++n)
                yb[row * C_ + h * HS_ + n * 16 + lr] = f2bf(acc[m][n][j] * inv);
        }
    }
}

// ---------------- launch ----------------

extern "C" void kernel_launch(void* const* d_in, const int* in_sizes, int n_in,
                              void* d_out, int out_size, void* d_ws, size_t ws_size,
                              hipStream_t stream) {
    const float* x      = (const float*)d_in[0];
    const float* memory = (const float*)d_in[1];
    const float* Wq     = (const float*)d_in[2];
    const float* bq     = (const float*)d_in[3];
    const float* Wkv    = (const float*)d_in[4];
    const float* bkv    = (const float*)d_in[5];
    const float* Wproj  = (const float*)d_in[6];
    const float* bproj  = (const float*)d_in[7];

    char* ws = (char*)d_ws;
    size_t off = 0;
    auto alloc = [&](size_t bytes) { char* p = ws + off; off += (bytes + 255) & ~(size_t)255; return p; };
    short* xb   = (short*)alloc((size_t)8192 * 768 * 2);   // x bf16, reused as y after attention
    short* memb = (short*)alloc((size_t)8192 * 768 * 2);
    short* qb   = (short*)alloc((size_t)8192 * 768 * 2);
    short* ktb  = (short*)alloc((size_t)B_ * H_ * T_ * 64 * 2);   // K, block-XOR swizzled
    short* vtb  = (short*)alloc((size_t)B_ * H_ * HS_ * T_ * 2);  // V^T, sigma+XOR
    short* WqT  = (short*)alloc((size_t)768 * 768 * 2);
    short* WkvT = (short*)alloc((size_t)1536 * 768 * 2);
    short* WpT  = (short*)alloc((size_t)768 * 768 * 2);

    // scale folded into Wq/bq: log2(e)/sqrt(HS) -> attention P = exp2(S) raw
    const float qscale = 1.4426950408889634f / 8.0f;

    prepass<<<12288 + 2304, 256, 0, stream>>>(x, xb, memory, memb,
                                              Wq, WqT, Wkv, WkvT, Wproj, WpT, qscale);
    gemm_qkv<<<dim3(18, 64), 256, 0, stream>>>(xb, memb, WqT, WkvT, bq, bkv, qb, ktb, vtb, qscale);
    attn_fwd18<<<dim3(16 * 48), 256, 0, stream>>>(qb, ktb, vtb, xb /* y reuses xb */);
    gemm_out<<<dim3(6, 64), 256, 0, stream>>>(xb, WpT, bproj, (float*)d_out);
}

// Round 22
// 167.536 us; speedup vs baseline: 1.0463x; 1.0296x over previous
//
#include <hip/hip_runtime.h>
#include <hip/hip_bf16.h>

// MultiCrossAttention: B=4, T=2048, C=768, H=12, HS=64
// R22: R18's exact GEMM/prepass/global-layout config (XOR'd ktb/vtb) +
// R20's exact attn dataflow (reg-staged dbuf, padded LDS, linear read cols,
// 90.3us across 4 runs). The global XOR is undone at ds_write time via
// thread-constant XOR-corrected columns, so LDS holds the logical layout.

#define B_  4
#define T_  2048
#define C_  768
#define H_  12
#define HS_ 64

typedef __attribute__((ext_vector_type(8))) short short8;   // 8 bf16 (4 VGPRs)
typedef __attribute__((ext_vector_type(4))) float f32x4;

__device__ __forceinline__ short f2bf(float f) {
    __hip_bfloat16 h = __float2bfloat16(f);
    return *reinterpret_cast<short*>(&h);
}

// async global -> LDS, 16B per lane; LDS dest = wave-uniform base + lane*16
__device__ __forceinline__ void gload_lds16(const void* g, void* l) {
    __builtin_amdgcn_global_load_lds((const __attribute__((address_space(1))) void*)g,
                                     (__attribute__((address_space(3))) void*)l,
                                     16, 0, 0);
}

// ---------------- prepass: cvt(x), cvt(memory), transpose 3 weights ----------

__global__ void prepass(const float* __restrict__ x, short* __restrict__ xb,
                        const float* __restrict__ mem, short* __restrict__ memb,
                        const float* __restrict__ Wq,  short* __restrict__ WqT,
                        const float* __restrict__ Wkv, short* __restrict__ WkvT,
                        const float* __restrict__ Wp,  short* __restrict__ WpT,
                        float qscale) {
    const int n4 = 8192 * 768 / 4;          // float4 per tensor
    const int cvtblocks = (2 * n4) / 256;   // 12288
    int bid = blockIdx.x;
    if (bid < cvtblocks) {
        int i = bid * 256 + threadIdx.x;
        const float* in; short* out;
        if (i < n4) { in = x; out = xb; }
        else        { in = mem; out = memb; i -= n4; }
        float4 v = reinterpret_cast<const float4*>(in)[i];
        short4 o;
        o.x = f2bf(v.x); o.y = f2bf(v.y); o.z = f2bf(v.z); o.w = f2bf(v.w);
        reinterpret_cast<short4*>(out)[i] = o;
        return;
    }
    // tiled transpose: out[n][k] = bf16(in[k][n]*sc), 32x32 tiles via LDS
    __shared__ float tile[32][33];
    bid -= cvtblocks;
    const float* in; short* out; int N; float sc = 1.0f;
    if (bid < 576)       { in = Wq;  out = WqT;  N = 768;  sc = qscale; }
    else if (bid < 1728) { in = Wkv; out = WkvT; N = 1536; bid -= 576; }
    else                 { in = Wp;  out = WpT;  N = 768;  bid -= 1728; }
    const int tiles_n = N >> 5;
    const int k0 = (bid / tiles_n) * 32;
    const int n0 = (bid % tiles_n) * 32;
    const int r = threadIdx.x >> 5;     // 0..7
    const int c = threadIdx.x & 31;
    #pragma unroll
    for (int i = 0; i < 4; ++i)
        tile[r + 8 * i][c] = in[(size_t)(k0 + r + 8 * i) * N + n0 + c];
    __syncthreads();
    #pragma unroll
    for (int i = 0; i < 4; ++i)
        out[(size_t)(n0 + r + 8 * i) * 768 + k0 + c] = f2bf(tile[c][r + 8 * i] * sc);
}

// ---------------- GEMM bodies (m97 structure) ----------------

template<int OUT_F32, int WRITE_KV>
__device__ __forceinline__ void gemm_body(const short* __restrict__ A, const short* __restrict__ BT,
                                          const float* __restrict__ bias, void* __restrict__ out,
                                          short* __restrict__ kt, short* __restrict__ vt,
                                          int m0, int n0, int K, int ldo, float bscale,
                                          short (*As)[64], short (*Bs)[64]) {
    const int t  = threadIdx.x;
    const int wid = t >> 6;
    const int wm = wid >> 1, wn = wid & 1;
    const int lane = t & 63;
    const int lr = lane & 15;
    const int lk = (lane >> 4) * 8;

    f32x4 acc[4][4] = {};

    const int srow = wid * 32 + (lane >> 3);   // staging row (+ i*8)
    const int scol = (lane & 7) * 8;           // staging col (shorts)

    for (int k0 = 0; k0 < K; k0 += 64) {
        __syncthreads();
        #pragma unroll
        for (int i = 0; i < 4; ++i)
            gload_lds16(&A[(size_t)(m0 + srow + i * 8) * K + k0 + scol],
                        &As[wid * 32 + i * 8][0]);
        #pragma unroll
        for (int i = 0; i < 4; ++i)
            gload_lds16(&BT[(size_t)(n0 + srow + i * 8) * K + k0 + scol],
                        &Bs[wid * 32 + i * 8][0]);
        __syncthreads();

        #pragma unroll
        for (int ks = 0; ks < 2; ++ks) {
            const int kk = ks * 32 + lk;
            short8 a[4], b[4];
            #pragma unroll
            for (int m = 0; m < 4; ++m)
                a[m] = *reinterpret_cast<const short8*>(&As[wm*64 + m*16 + lr][kk]);
            #pragma unroll
            for (int n = 0; n < 4; ++n)
                b[n] = *reinterpret_cast<const short8*>(&Bs[wn*64 + n*16 + lr][kk]);
            #pragma unroll
            for (int m = 0; m < 4; ++m)
                #pragma unroll
                for (int n = 0; n < 4; ++n)
                    acc[m][n] = __builtin_amdgcn_mfma_f32_16x16x32_bf16(a[m], b[n], acc[m][n], 0, 0, 0);
        }
    }

    const int rb = m0 + wm * 64;
    const int cb = n0 + wn * 64;
    const int rj = (lane >> 4) * 4;
    #pragma unroll
    for (int n = 0; n < 4; ++n) {
        const int col = cb + n * 16 + lr;
        const float bv = bias[col] * bscale;
        #pragma unroll
        for (int m = 0; m < 4; ++m) {
            #pragma unroll
            for (int j = 0; j < 4; ++j) {
                const int row = rb + m * 16 + rj + j;
                const float v = acc[m][n][j] + bv;
                if (WRITE_KV) {
                    const int bb = row >> 11, tt = row & 2047;
                    if (col < 768) {
                        // K -> ktb [b][h][t][64], 16B-block XOR by (t&7)
                        const int hh = col >> 6, dd = col & 63;
                        const int s = ((((dd >> 3) ^ (tt & 7)) << 3) | (dd & 7));
                        kt[(((size_t)bb * H_ + hh) * T_ + tt) * 64 + s] = f2bf(v);
                    } else {
                        // V -> vtb [b][h][64][T], sigma within chunk + block XOR by (d&7)
                        const int vd = col - 768;
                        const int hh = vd >> 6, dd = vd & 63;
                        const int kv = tt & 63;
                        const int slot = 32 * (kv >> 5) + 8 * ((kv >> 2) & 3)
                                       + 4 * ((kv >> 4) & 1) + (kv & 3);
                        const int slot2 = (((slot >> 3) ^ (dd & 7)) << 3) | (slot & 7);
                        vt[(((size_t)bb * H_ + hh) * HS_ + dd) * T_ + (tt & ~63) + slot2] = f2bf(v);
                    }
                } else if (OUT_F32) {
                    reinterpret_cast<float*>(out)[(size_t)row * ldo + col] = v;
                } else {
                    reinterpret_cast<short*>(out)[(size_t)row * ldo + col] = f2bf(v);
                }
            }
        }
    }
}

// merged q + kv projection GEMM: grid (18, 64), chunked XCD swizzle
__global__ void gemm_qkv(const short* __restrict__ xb,  const short* __restrict__ memb,
                         const short* __restrict__ WqT, const short* __restrict__ WkvT,
                         const float* __restrict__ bq,  const float* __restrict__ bkv,
                         short* __restrict__ qb, short* __restrict__ kt,
                         short* __restrict__ vt, float qscale) {
    __shared__ short As[128][64];
    __shared__ short Bs[128][64];
    const int lin = blockIdx.y * 18 + blockIdx.x;
    const int swz = (lin % 8) * 144 + lin / 8;
    const int bx = swz % 18;
    const int m0 = (swz / 18) * 128;
    if (bx < 6) {
        gemm_body<0,0>(xb, WqT, bq, qb, nullptr, nullptr, m0, bx * 128, 768, 768, qscale, As, Bs);
    } else {
        gemm_body<0,1>(memb, WkvT, bkv, nullptr, kt, vt, m0, (bx - 6) * 128, 768, 1536, 1.0f, As, Bs);
    }
}

// output projection GEMM (f32 out): grid (6, 64), chunked XCD swizzle
__global__ void gemm_out(const short* __restrict__ yb, const short* __restrict__ WpT,
                         const float* __restrict__ bproj, float* __restrict__ out) {
    __shared__ short As[128][64];
    __shared__ short Bs[128][64];
    const int lin = blockIdx.y * 6 + blockIdx.x;
    const int swz = (lin % 8) * 48 + lin / 8;
    gemm_body<1,0>(yb, WpT, bproj, out, nullptr, nullptr, (swz / 6) * 128, (swz % 6) * 128,
                   768, 768, 1.0f, As, Bs);
}

// ---------------- flash attention (reg-staged dbuf, un-XOR at ds_write) -----
// grid 768 = 16 qblk x 48 pairs. Block 256 = 4 waves, wave owns 32 q-rows.
// Per chunk: ds_write buf[c] at XOR-corrected cols (thread-constant) ->
// issue loads t+1 -> barrier -> compute buf[c] (R20's linear cols) -> c^=1.
// ktb/vtb rows carry a 16B-block XOR in GLOBAL; writing block q's data to
// LDS col (q^(row&7))*8 restores the logical layout (XOR is an involution,
// bijective per row). Swapped QK^T (lane owns a q-row of P), register-local
// PV A-frag (sigma), ones-MFMA l, shift-free softmax (Wq pre-scaled log2e/8).

__global__ void __launch_bounds__(256)
attn_fwd19(const short* __restrict__ qb, const short* __restrict__ ktb,
           const short* __restrict__ vtb, short* __restrict__ yb) {
    __shared__ short Ks[2][64][72];
    __shared__ short Vt[2][64][72];

    const int id = blockIdx.x;
    const int pair = id % 48;        // b*H + h
    const int b = pair / H_, h = pair % H_;
    const int q0 = (id / 48) * 128;
    const int t = threadIdx.x;
    const int w = t >> 6;
    const int lane = t & 63;
    const int lr = lane & 15;
    const int g = lane >> 4;

    const int str = t >> 2;          // staging row 0..63 (4 threads/row)
    const int stc = (t & 3) * 16;    // staging col base in GLOBAL (s-blocks stc/8, stc/8+1)
    const int x8  = str & 7;         // per-row XOR key
    const int wc0 = (((stc >> 3) ^ x8) << 3);        // LDS col of 1st block's data
    const int wc1 = ((((stc >> 3) + 1) ^ x8) << 3);  // LDS col of 2nd block's data

    const short* Kb = ktb + (size_t)(b * H_ + h) * T_ * 64;
    const short* Vb = vtb + (size_t)(b * H_ + h) * HS_ * T_;

    // Q fragments: tile m rows q0 + w*32 + m*16 + lr, k = ks*32+g*8
    short8 aq[2][2];
    #pragma unroll
    for (int m = 0; m < 2; ++m)
        #pragma unroll
        for (int ks = 0; ks < 2; ++ks)
            aq[m][ks] = *reinterpret_cast<const short8*>(
                &qb[(size_t)(b * T_ + q0 + w * 32 + m * 16 + lr) * C_ + h * HS_ + ks * 32 + g * 8]);

    // all-ones bf16 B-fragment for the l-sum MFMA
    short8 ones8;
    #pragma unroll
    for (int i = 0; i < 8; ++i) ones8[i] = (short)0x3F80;

    f32x4 acc[2][4] = {};
    f32x4 accl[2] = {};

    // prologue: load chunk 0 into regs (K rows dense 64-wide; V rows T-wide)
    uint4 kr0, kr1, vr0, vr1;
    {
        const short* gk = &Kb[(size_t)str * 64 + stc];
        const short* gv = &Vb[(size_t)str * T_ + stc];
        kr0 = *reinterpret_cast<const uint4*>(gk);
        kr1 = *reinterpret_cast<const uint4*>(gk + 8);
        vr0 = *reinterpret_cast<const uint4*>(gv);
        vr1 = *reinterpret_cast<const uint4*>(gv + 8);
    }

    int c = 0;
    for (int kv0 = 0; kv0 < T_; kv0 += 64) {
        // stage chunk t into buf[c] at XOR-corrected (logical) columns
        *reinterpret_cast<uint4*>(&Ks[c][str][wc0]) = kr0;
        *reinterpret_cast<uint4*>(&Ks[c][str][wc1]) = kr1;
        *reinterpret_cast<uint4*>(&Vt[c][str][wc0]) = vr0;
        *reinterpret_cast<uint4*>(&Vt[c][str][wc1]) = vr1;

        // issue loads for chunk t+1 before the barrier
        if (kv0 + 64 < T_) {
            const short* gk = &Kb[(size_t)(kv0 + 64 + str) * 64 + stc];
            const short* gv = &Vb[(size_t)str * T_ + kv0 + 64 + stc];
            kr0 = *reinterpret_cast<const uint4*>(gk);
            kr1 = *reinterpret_cast<const uint4*>(gk + 8);
            vr0 = *reinterpret_cast<const uint4*>(gv);
            vr1 = *reinterpret_cast<const uint4*>(gv + 8);
        }

        __syncthreads();   // buf[c] fully staged by all waves

        // S^T = K Q^T for both m-tiles (bk read once, used twice; linear cols)
        f32x4 s[2][4] = {};
        #pragma unroll
        for (int ks = 0; ks < 2; ++ks) {
            #pragma unroll
            for (int n = 0; n < 4; ++n) {
                short8 bk = *reinterpret_cast<const short8*>(&Ks[c][n * 16 + lr][ks * 32 + g * 8]);
                #pragma unroll
                for (int m = 0; m < 2; ++m)
                    s[m][n] = __builtin_amdgcn_mfma_f32_16x16x32_bf16(bk, aq[m][ks], s[m][n], 0, 0, 0);
            }
        }

        // P = exp2(S), pack PV A-frags (register-local under sigma)
        short8 pa[2][2];
        #pragma unroll
        for (int m = 0; m < 2; ++m) {
            #pragma unroll
            for (int n = 0; n < 4; ++n) {
                #pragma unroll
                for (int j = 0; j < 4; ++j)
                    s[m][n][j] = exp2f(s[m][n][j]);
            }
            #pragma unroll
            for (int ks = 0; ks < 2; ++ks) {
                pa[m][ks][0] = f2bf(s[m][2*ks][0]); pa[m][ks][1] = f2bf(s[m][2*ks][1]);
                pa[m][ks][2] = f2bf(s[m][2*ks][2]); pa[m][ks][3] = f2bf(s[m][2*ks][3]);
                pa[m][ks][4] = f2bf(s[m][2*ks+1][0]); pa[m][ks][5] = f2bf(s[m][2*ks+1][1]);
                pa[m][ks][6] = f2bf(s[m][2*ks+1][2]); pa[m][ks][7] = f2bf(s[m][2*ks+1][3]);
            }
        }

        // Y += P @ V ; l += P @ ones (bv read once, used by both m)
        #pragma unroll
        for (int ks = 0; ks < 2; ++ks) {
            #pragma unroll
            for (int m = 0; m < 2; ++m)
                accl[m] = __builtin_amdgcn_mfma_f32_16x16x32_bf16(pa[m][ks], ones8, accl[m], 0, 0, 0);
            #pragma unroll
            for (int n = 0; n < 4; ++n) {
                short8 bv = *reinterpret_cast<const short8*>(&Vt[c][n * 16 + lr][ks * 32 + g * 8]);
                #pragma unroll
                for (int m = 0; m < 2; ++m)
                    acc[m][n] = __builtin_amdgcn_mfma_f32_16x16x32_bf16(pa[m][ks], bv, acc[m][n], 0, 0, 0);
            }
        }

        c ^= 1;
    }

    // epilogue: y = acc / l ; accl[m][j] holds l for q-row g*4+j of tile m
    #pragma unroll
    for (int m = 0; m < 2; ++m) {
        #pragma unroll
        for (int j = 0; j < 4; ++j) {
            const float inv = 1.f / accl[m][j];
            const size_t row = (size_t)(b * T_ + q0 + w * 32 + m * 16 + g * 4 + j);
            #pragma unroll
            for (int n = 0; n < 4; ++n)
                yb[row * C_ + h * HS_ + n * 16 + lr] = f2bf(acc[m][n][j] * inv);
        }
    }
}

// ---------------- launch ----------------

extern "C" void kernel_launch(void* const* d_in, const int* in_sizes, int n_in,
                              void* d_out, int out_size, void* d_ws, size_t ws_size,
                              hipStream_t stream) {
    const float* x      = (const float*)d_in[0];
    const float* memory = (const float*)d_in[1];
    const float* Wq     = (const float*)d_in[2];
    const float* bq     = (const float*)d_in[3];
    const float* Wkv    = (const float*)d_in[4];
    const float* bkv    = (const float*)d_in[5];
    const float* Wproj  = (const float*)d_in[6];
    const float* bproj  = (const float*)d_in[7];

    char* ws = (char*)d_ws;
    size_t off = 0;
    auto alloc = [&](size_t bytes) { char* p = ws + off; off += (bytes + 255) & ~(size_t)255; return p; };
    short* xb   = (short*)alloc((size_t)8192 * 768 * 2);   // x bf16, reused as y after attention
    short* memb = (short*)alloc((size_t)8192 * 768 * 2);
    short* qb   = (short*)alloc((size_t)8192 * 768 * 2);
    short* ktb  = (short*)alloc((size_t)B_ * H_ * T_ * 64 * 2);   // K, block-XOR swizzled
    short* vtb  = (short*)alloc((size_t)B_ * H_ * HS_ * T_ * 2);  // V^T, sigma+XOR
    short* WqT  = (short*)alloc((size_t)768 * 768 * 2);
    short* WkvT = (short*)alloc((size_t)1536 * 768 * 2);
    short* WpT  = (short*)alloc((size_t)768 * 768 * 2);

    // scale folded into Wq/bq: log2(e)/sqrt(HS) -> attention P = exp2(S) raw
    const float qscale = 1.4426950408889634f / 8.0f;

    prepass<<<12288 + 2304, 256, 0, stream>>>(x, xb, memory, memb,
                                              Wq, WqT, Wkv, WkvT, Wproj, WpT, qscale);
    gemm_qkv<<<dim3(18, 64), 256, 0, stream>>>(xb, memb, WqT, WkvT, bq, bkv, qb, ktb, vtb, qscale);
    attn_fwd19<<<dim3(16 * 48), 256, 0, stream>>>(qb, ktb, vtb, xb /* y reuses xb */);
    gemm_out<<<dim3(6, 64), 256, 0, stream>>>(xb, WpT, bproj, (float*)d_out);
}

// Round 23
// 166.901 us; speedup vs baseline: 1.0503x; 1.0038x over previous
//
#include <hip/hip_runtime.h>
#include <hip/hip_bf16.h>

// MultiCrossAttention: B=4, T=2048, C=768, H=12, HS=64
// R23: R22 + two attn VALU cuts: (1) P->bf16 via v_cvt_pk_bf16_f32 (1 op per
// float pair, RNE — replaces multi-op __float2bfloat16 + pack moves);
// (2) QK^T ks=0 MFMAs write fresh through a persistent zero C-in quad
// (no per-chunk re-zeroing of the 32 s-registers). Dataflow unchanged.

#define B_  4
#define T_  2048
#define C_  768
#define H_  12
#define HS_ 64

typedef __attribute__((ext_vector_type(8))) short short8;   // 8 bf16 (4 VGPRs)
typedef __attribute__((ext_vector_type(4))) float f32x4;

__device__ __forceinline__ short f2bf(float f) {
    __hip_bfloat16 h = __float2bfloat16(f);
    return *reinterpret_cast<short*>(&h);
}

// packed f32x2 -> bf16x2 (RNE), single v_cvt_pk_bf16_f32 (no builtin on gfx950)
__device__ __forceinline__ unsigned cvtpk(float lo, float hi) {
    unsigned r;
    asm("v_cvt_pk_bf16_f32 %0, %1, %2" : "=v"(r) : "v"(lo), "v"(hi));
    return r;
}

// async global -> LDS, 16B per lane; LDS dest = wave-uniform base + lane*16
__device__ __forceinline__ void gload_lds16(const void* g, void* l) {
    __builtin_amdgcn_global_load_lds((const __attribute__((address_space(1))) void*)g,
                                     (__attribute__((address_space(3))) void*)l,
                                     16, 0, 0);
}

// ---------------- prepass: cvt(x), cvt(memory), transpose 3 weights ----------

__global__ void prepass(const float* __restrict__ x, short* __restrict__ xb,
                        const float* __restrict__ mem, short* __restrict__ memb,
                        const float* __restrict__ Wq,  short* __restrict__ WqT,
                        const float* __restrict__ Wkv, short* __restrict__ WkvT,
                        const float* __restrict__ Wp,  short* __restrict__ WpT,
                        float qscale) {
    const int n4 = 8192 * 768 / 4;          // float4 per tensor
    const int cvtblocks = (2 * n4) / 256;   // 12288
    int bid = blockIdx.x;
    if (bid < cvtblocks) {
        int i = bid * 256 + threadIdx.x;
        const float* in; short* out;
        if (i < n4) { in = x; out = xb; }
        else        { in = mem; out = memb; i -= n4; }
        float4 v = reinterpret_cast<const float4*>(in)[i];
        short4 o;
        o.x = f2bf(v.x); o.y = f2bf(v.y); o.z = f2bf(v.z); o.w = f2bf(v.w);
        reinterpret_cast<short4*>(out)[i] = o;
        return;
    }
    // tiled transpose: out[n][k] = bf16(in[k][n]*sc), 32x32 tiles via LDS
    __shared__ float tile[32][33];
    bid -= cvtblocks;
    const float* in; short* out; int N; float sc = 1.0f;
    if (bid < 576)       { in = Wq;  out = WqT;  N = 768;  sc = qscale; }
    else if (bid < 1728) { in = Wkv; out = WkvT; N = 1536; bid -= 576; }
    else                 { in = Wp;  out = WpT;  N = 768;  bid -= 1728; }
    const int tiles_n = N >> 5;
    const int k0 = (bid / tiles_n) * 32;
    const int n0 = (bid % tiles_n) * 32;
    const int r = threadIdx.x >> 5;     // 0..7
    const int c = threadIdx.x & 31;
    #pragma unroll
    for (int i = 0; i < 4; ++i)
        tile[r + 8 * i][c] = in[(size_t)(k0 + r + 8 * i) * N + n0 + c];
    __syncthreads();
    #pragma unroll
    for (int i = 0; i < 4; ++i)
        out[(size_t)(n0 + r + 8 * i) * 768 + k0 + c] = f2bf(tile[c][r + 8 * i] * sc);
}

// ---------------- GEMM bodies (m97 structure) ----------------

template<int OUT_F32, int WRITE_KV>
__device__ __forceinline__ void gemm_body(const short* __restrict__ A, const short* __restrict__ BT,
                                          const float* __restrict__ bias, void* __restrict__ out,
                                          short* __restrict__ kt, short* __restrict__ vt,
                                          int m0, int n0, int K, int ldo, float bscale,
                                          short (*As)[64], short (*Bs)[64]) {
    const int t  = threadIdx.x;
    const int wid = t >> 6;
    const int wm = wid >> 1, wn = wid & 1;
    const int lane = t & 63;
    const int lr = lane & 15;
    const int lk = (lane >> 4) * 8;

    f32x4 acc[4][4] = {};

    const int srow = wid * 32 + (lane >> 3);   // staging row (+ i*8)
    const int scol = (lane & 7) * 8;           // staging col (shorts)

    for (int k0 = 0; k0 < K; k0 += 64) {
        __syncthreads();
        #pragma unroll
        for (int i = 0; i < 4; ++i)
            gload_lds16(&A[(size_t)(m0 + srow + i * 8) * K + k0 + scol],
                        &As[wid * 32 + i * 8][0]);
        #pragma unroll
        for (int i = 0; i < 4; ++i)
            gload_lds16(&BT[(size_t)(n0 + srow + i * 8) * K + k0 + scol],
                        &Bs[wid * 32 + i * 8][0]);
        __syncthreads();

        #pragma unroll
        for (int ks = 0; ks < 2; ++ks) {
            const int kk = ks * 32 + lk;
            short8 a[4], b[4];
            #pragma unroll
            for (int m = 0; m < 4; ++m)
                a[m] = *reinterpret_cast<const short8*>(&As[wm*64 + m*16 + lr][kk]);
            #pragma unroll
            for (int n = 0; n < 4; ++n)
                b[n] = *reinterpret_cast<const short8*>(&Bs[wn*64 + n*16 + lr][kk]);
            #pragma unroll
            for (int m = 0; m < 4; ++m)
                #pragma unroll
                for (int n = 0; n < 4; ++n)
                    acc[m][n] = __builtin_amdgcn_mfma_f32_16x16x32_bf16(a[m], b[n], acc[m][n], 0, 0, 0);
        }
    }

    const int rb = m0 + wm * 64;
    const int cb = n0 + wn * 64;
    const int rj = (lane >> 4) * 4;
    #pragma unroll
    for (int n = 0; n < 4; ++n) {
        const int col = cb + n * 16 + lr;
        const float bv = bias[col] * bscale;
        #pragma unroll
        for (int m = 0; m < 4; ++m) {
            #pragma unroll
            for (int j = 0; j < 4; ++j) {
                const int row = rb + m * 16 + rj + j;
                const float v = acc[m][n][j] + bv;
                if (WRITE_KV) {
                    const int bb = row >> 11, tt = row & 2047;
                    if (col < 768) {
                        // K -> ktb [b][h][t][64], 16B-block XOR by (t&7)
                        const int hh = col >> 6, dd = col & 63;
                        const int s = ((((dd >> 3) ^ (tt & 7)) << 3) | (dd & 7));
                        kt[(((size_t)bb * H_ + hh) * T_ + tt) * 64 + s] = f2bf(v);
                    } else {
                        // V -> vtb [b][h][64][T], sigma within chunk + block XOR by (d&7)
                        const int vd = col - 768;
                        const int hh = vd >> 6, dd = vd & 63;
                        const int kv = tt & 63;
                        const int slot = 32 * (kv >> 5) + 8 * ((kv >> 2) & 3)
                                       + 4 * ((kv >> 4) & 1) + (kv & 3);
                        const int slot2 = (((slot >> 3) ^ (dd & 7)) << 3) | (slot & 7);
                        vt[(((size_t)bb * H_ + hh) * HS_ + dd) * T_ + (tt & ~63) + slot2] = f2bf(v);
                    }
                } else if (OUT_F32) {
                    reinterpret_cast<float*>(out)[(size_t)row * ldo + col] = v;
                } else {
                    reinterpret_cast<short*>(out)[(size_t)row * ldo + col] = f2bf(v);
                }
            }
        }
    }
}

// merged q + kv projection GEMM: grid (18, 64), chunked XCD swizzle
__global__ void gemm_qkv(const short* __restrict__ xb,  const short* __restrict__ memb,
                         const short* __restrict__ WqT, const short* __restrict__ WkvT,
                         const float* __restrict__ bq,  const float* __restrict__ bkv,
                         short* __restrict__ qb, short* __restrict__ kt,
                         short* __restrict__ vt, float qscale) {
    __shared__ short As[128][64];
    __shared__ short Bs[128][64];
    const int lin = blockIdx.y * 18 + blockIdx.x;
    const int swz = (lin % 8) * 144 + lin / 8;
    const int bx = swz % 18;
    const int m0 = (swz / 18) * 128;
    if (bx < 6) {
        gemm_body<0,0>(xb, WqT, bq, qb, nullptr, nullptr, m0, bx * 128, 768, 768, qscale, As, Bs);
    } else {
        gemm_body<0,1>(memb, WkvT, bkv, nullptr, kt, vt, m0, (bx - 6) * 128, 768, 1536, 1.0f, As, Bs);
    }
}

// output projection GEMM (f32 out): grid (6, 64), chunked XCD swizzle
__global__ void gemm_out(const short* __restrict__ yb, const short* __restrict__ WpT,
                         const float* __restrict__ bproj, float* __restrict__ out) {
    __shared__ short As[128][64];
    __shared__ short Bs[128][64];
    const int lin = blockIdx.y * 6 + blockIdx.x;
    const int swz = (lin % 8) * 48 + lin / 8;
    gemm_body<1,0>(yb, WpT, bproj, out, nullptr, nullptr, (swz / 6) * 128, (swz % 6) * 128,
                   768, 768, 1.0f, As, Bs);
}

// ---------------- flash attention (R22 dataflow + cvt_pk P, zero-C-in) ------
// grid 768 = 16 qblk x 48 pairs. Block 256 = 4 waves, wave owns 32 q-rows.
// Per chunk: ds_write buf[c] at XOR-corrected cols (thread-constant) ->
// issue loads t+1 -> barrier -> compute buf[c] (linear cols) -> c^=1.
// QK^T ks=0 writes s fresh via persistent zero C-in (no per-chunk zeroing);
// P->bf16 via v_cvt_pk_bf16_f32 (RNE, 4 ops per A-frag). Swapped QK^T,
// register-local PV A-frag (sigma), ones-MFMA l, shift-free softmax.

__global__ void __launch_bounds__(256)
attn_fwd20(const short* __restrict__ qb, const short* __restrict__ ktb,
           const short* __restrict__ vtb, short* __restrict__ yb) {
    __shared__ short Ks[2][64][72];
    __shared__ short Vt[2][64][72];

    const int id = blockIdx.x;
    const int pair = id % 48;        // b*H + h
    const int b = pair / H_, h = pair % H_;
    const int q0 = (id / 48) * 128;
    const int t = threadIdx.x;
    const int w = t >> 6;
    const int lane = t & 63;
    const int lr = lane & 15;
    const int g = lane >> 4;

    const int str = t >> 2;          // staging row 0..63 (4 threads/row)
    const int stc = (t & 3) * 16;    // staging col base in GLOBAL
    const int x8  = str & 7;         // per-row XOR key
    const int wc0 = (((stc >> 3) ^ x8) << 3);        // LDS col of 1st block's data
    const int wc1 = ((((stc >> 3) + 1) ^ x8) << 3);  // LDS col of 2nd block's data

    const short* Kb = ktb + (size_t)(b * H_ + h) * T_ * 64;
    const short* Vb = vtb + (size_t)(b * H_ + h) * HS_ * T_;

    // Q fragments: tile m rows q0 + w*32 + m*16 + lr, k = ks*32+g*8
    short8 aq[2][2];
    #pragma unroll
    for (int m = 0; m < 2; ++m)
        #pragma unroll
        for (int ks = 0; ks < 2; ++ks)
            aq[m][ks] = *reinterpret_cast<const short8*>(
                &qb[(size_t)(b * T_ + q0 + w * 32 + m * 16 + lr) * C_ + h * HS_ + ks * 32 + g * 8]);

    // all-ones bf16 B-fragment for the l-sum MFMA; persistent zero C-in quad
    short8 ones8;
    #pragma unroll
    for (int i = 0; i < 8; ++i) ones8[i] = (short)0x3F80;
    const f32x4 z4 = {0.f, 0.f, 0.f, 0.f};

    f32x4 acc[2][4] = {};
    f32x4 accl[2] = {};

    // prologue: load chunk 0 into regs (K rows dense 64-wide; V rows T-wide)
    uint4 kr0, kr1, vr0, vr1;
    {
        const short* gk = &Kb[(size_t)str * 64 + stc];
        const short* gv = &Vb[(size_t)str * T_ + stc];
        kr0 = *reinterpret_cast<const uint4*>(gk);
        kr1 = *reinterpret_cast<const uint4*>(gk + 8);
        vr0 = *reinterpret_cast<const uint4*>(gv);
        vr1 = *reinterpret_cast<const uint4*>(gv + 8);
    }

    int c = 0;
    for (int kv0 = 0; kv0 < T_; kv0 += 64) {
        // stage chunk t into buf[c] at XOR-corrected (logical) columns
        *reinterpret_cast<uint4*>(&Ks[c][str][wc0]) = kr0;
        *reinterpret_cast<uint4*>(&Ks[c][str][wc1]) = kr1;
        *reinterpret_cast<uint4*>(&Vt[c][str][wc0]) = vr0;
        *reinterpret_cast<uint4*>(&Vt[c][str][wc1]) = vr1;

        // issue loads for chunk t+1 before the barrier
        if (kv0 + 64 < T_) {
            const short* gk = &Kb[(size_t)(kv0 + 64 + str) * 64 + stc];
            const short* gv = &Vb[(size_t)str * T_ + kv0 + 64 + stc];
            kr0 = *reinterpret_cast<const uint4*>(gk);
            kr1 = *reinterpret_cast<const uint4*>(gk + 8);
            vr0 = *reinterpret_cast<const uint4*>(gv);
            vr1 = *reinterpret_cast<const uint4*>(gv + 8);
        }

        __syncthreads();   // buf[c] fully staged by all waves

        // S^T = K Q^T; ks=0 writes fresh (zero C-in), ks=1 accumulates
        f32x4 s[2][4];
        #pragma unroll
        for (int n = 0; n < 4; ++n) {
            short8 bk = *reinterpret_cast<const short8*>(&Ks[c][n * 16 + lr][g * 8]);
            #pragma unroll
            for (int m = 0; m < 2; ++m)
                s[m][n] = __builtin_amdgcn_mfma_f32_16x16x32_bf16(bk, aq[m][0], z4, 0, 0, 0);
        }
        #pragma unroll
        for (int n = 0; n < 4; ++n) {
            short8 bk = *reinterpret_cast<const short8*>(&Ks[c][n * 16 + lr][32 + g * 8]);
            #pragma unroll
            for (int m = 0; m < 2; ++m)
                s[m][n] = __builtin_amdgcn_mfma_f32_16x16x32_bf16(bk, aq[m][1], s[m][n], 0, 0, 0);
        }

        // P = exp2(S); pack PV A-frags via v_cvt_pk_bf16_f32 (RNE)
        short8 pa[2][2];
        #pragma unroll
        for (int m = 0; m < 2; ++m) {
            #pragma unroll
            for (int n = 0; n < 4; ++n) {
                #pragma unroll
                for (int j = 0; j < 4; ++j)
                    s[m][n][j] = exp2f(s[m][n][j]);
            }
            #pragma unroll
            for (int ks = 0; ks < 2; ++ks) {
                uint4 u;
                u.x = cvtpk(s[m][2*ks][0],   s[m][2*ks][1]);
                u.y = cvtpk(s[m][2*ks][2],   s[m][2*ks][3]);
                u.z = cvtpk(s[m][2*ks+1][0], s[m][2*ks+1][1]);
                u.w = cvtpk(s[m][2*ks+1][2], s[m][2*ks+1][3]);
                pa[m][ks] = __builtin_bit_cast(short8, u);
            }
        }

        // Y += P @ V ; l += P @ ones (bv read once, used by both m)
        #pragma unroll
        for (int ks = 0; ks < 2; ++ks) {
            #pragma unroll
            for (int m = 0; m < 2; ++m)
                accl[m] = __builtin_amdgcn_mfma_f32_16x16x32_bf16(pa[m][ks], ones8, accl[m], 0, 0, 0);
            #pragma unroll
            for (int n = 0; n < 4; ++n) {
                short8 bv = *reinterpret_cast<const short8*>(&Vt[c][n * 16 + lr][ks * 32 + g * 8]);
                #pragma unroll
                for (int m = 0; m < 2; ++m)
                    acc[m][n] = __builtin_amdgcn_mfma_f32_16x16x32_bf16(pa[m][ks], bv, acc[m][n], 0, 0, 0);
            }
        }

        c ^= 1;
    }

    // epilogue: y = acc / l ; accl[m][j] holds l for q-row g*4+j of tile m
    #pragma unroll
    for (int m = 0; m < 2; ++m) {
        #pragma unroll
        for (int j = 0; j < 4; ++j) {
            const float inv = 1.f / accl[m][j];
            const size_t row = (size_t)(b * T_ + q0 + w * 32 + m * 16 + g * 4 + j);
            #pragma unroll
            for (int n = 0; n < 4; ++n)
                yb[row * C_ + h * HS_ + n * 16 + lr] = f2bf(acc[m][n][j] * inv);
        }
    }
}

// ---------------- launch ----------------

extern "C" void kernel_launch(void* const* d_in, const int* in_sizes, int n_in,
                              void* d_out, int out_size, void* d_ws, size_t ws_size,
                              hipStream_t stream) {
    const float* x      = (const float*)d_in[0];
    const float* memory = (const float*)d_in[1];
    const float* Wq     = (const float*)d_in[2];
    const float* bq     = (const float*)d_in[3];
    const float* Wkv    = (const float*)d_in[4];
    const float* bkv    = (const float*)d_in[5];
    const float* Wproj  = (const float*)d_in[6];
    const float* bproj  = (const float*)d_in[7];

    char* ws = (char*)d_ws;
    size_t off = 0;
    auto alloc = [&](size_t bytes) { char* p = ws + off; off += (bytes + 255) & ~(size_t)255; return p; };
    short* xb   = (short*)alloc((size_t)8192 * 768 * 2);   // x bf16, reused as y after attention
    short* memb = (short*)alloc((size_t)8192 * 768 * 2);
    short* qb   = (short*)alloc((size_t)8192 * 768 * 2);
    short* ktb  = (short*)alloc((size_t)B_ * H_ * T_ * 64 * 2);   // K, block-XOR swizzled
    short* vtb  = (short*)alloc((size_t)B_ * H_ * HS_ * T_ * 2);  // V^T, sigma+XOR
    short* WqT  = (short*)alloc((size_t)768 * 768 * 2);
    short* WkvT = (short*)alloc((size_t)1536 * 768 * 2);
    short* WpT  = (short*)alloc((size_t)768 * 768 * 2);

    // scale folded into Wq/bq: log2(e)/sqrt(HS) -> attention P = exp2(S) raw
    const float qscale = 1.4426950408889634f / 8.0f;

    prepass<<<12288 + 2304, 256, 0, stream>>>(x, xb, memory, memb,
                                              Wq, WqT, Wkv, WkvT, Wproj, WpT, qscale);
    gemm_qkv<<<dim3(18, 64), 256, 0, stream>>>(xb, memb, WqT, WkvT, bq, bkv, qb, ktb, vtb, qscale);
    attn_fwd20<<<dim3(16 * 48), 256, 0, stream>>>(qb, ktb, vtb, xb /* y reuses xb */);
    gemm_out<<<dim3(6, 64), 256, 0, stream>>>(xb, WpT, bproj, (float*)d_out);
}